// Round 2
// baseline (841.282 us; speedup 1.0000x reference)
//
#include <hip/hip_runtime.h>
#include <math.h>

#define NN   50000
#define NE   800000
#define FEATD 128
#define SED  16
#define HD   64
#define NCLS 10
#define NLAY 3
#define NG   500

// ---------------- utility zero kernels (d_ws is poisoned 0xAA each call) ---
__global__ void zero_i32(int* __restrict__ p, int n){
    int i = blockIdx.x*blockDim.x + threadIdx.x;
    if (i < n) p[i] = 0;
}
__global__ void zero_f32(float* __restrict__ p, int n){
    int i = blockIdx.x*blockDim.x + threadIdx.x;
    if (i < n) p[i] = 0.f;
}

// ---------------- CSR build ------------------------------------------------
// NOTE: harness delivers integer inputs as int32 (const int*), NOT int64.
__global__ void count_deg(const int* __restrict__ dst, int* __restrict__ cnt, int e){
    int i = blockIdx.x*blockDim.x + threadIdx.x;
    if (i < e) atomicAdd(&cnt[dst[i]], 1);
}

// single-block scan over N=50000 counts; also emits cursor copy and dinv
__global__ __launch_bounds__(1024) void scan_off(const int* __restrict__ cnt,
        int* __restrict__ off, int* __restrict__ cur, float* __restrict__ dinv,
        int n, int etot){
    __shared__ int sums[1024];
    int t = threadIdx.x;
    int chunk = (n + 1023) / 1024;
    int lo = t * chunk; if (lo > n) lo = n;
    int hi = lo + chunk; if (hi > n) hi = n;
    int s = 0;
    for (int i = lo; i < hi; i++) s += cnt[i];
    sums[t] = s;
    __syncthreads();
    for (int d = 1; d < 1024; d <<= 1){
        int v = (t >= d) ? sums[t-d] : 0;
        __syncthreads();
        sums[t] += v;
        __syncthreads();
    }
    int run = (t == 0) ? 0 : sums[t-1];
    for (int i = lo; i < hi; i++){
        int c = cnt[i];
        off[i] = run; cur[i] = run;
        dinv[i] = rsqrtf((float)c + 1.0f);
        run += c;
    }
    if (t == 1023) off[n] = etot;
}

__global__ void fill_csr(const int* __restrict__ src, const int* __restrict__ dst,
        int* __restrict__ cur, int* __restrict__ csr, int e){
    int i = blockIdx.x*blockDim.x + threadIdx.x;
    if (i < e){
        int d = dst[i];
        int p = atomicAdd(&cur[d], 1);
        csr[p] = src[i];
    }
}

// ---------------- fp32 tall-skinny linear: out[n,64] = A[n,K]@W[K,64] (+b, act) ---
// Each wave handles 64 rows (lane=row) and a wave-uniform group of 16 cols so W
// goes through scalar loads. act: 0=none, 1=relu.
template<int K>
__global__ __launch_bounds__(256) void linear64(
        const float* __restrict__ A, int lda,
        const float* __restrict__ W,
        const float* __restrict__ bias,
        float* __restrict__ out, int ldo, int n, int act)
{
    int lane = threadIdx.x & 63;
    int c0 = __builtin_amdgcn_readfirstlane((threadIdx.x >> 6) << 4);
    int row = blockIdx.x * 64 + lane;
    if (row >= n) return;
    float acc[16];
#pragma unroll
    for (int j = 0; j < 16; j++) acc[j] = 0.f;
    const float* a  = A + (size_t)row * lda;
    const float* wp = W + c0;
    for (int k = 0; k < K; k += 4){
        float4 av = *(const float4*)(a + k);
        float aa[4] = {av.x, av.y, av.z, av.w};
#pragma unroll
        for (int kk = 0; kk < 4; kk++){
            const float* wr = wp + (k + kk) * 64;
#pragma unroll
            for (int j = 0; j < 16; j++)
                acc[j] = fmaf(aa[kk], wr[j], acc[j]);
        }
    }
    float* o = out + (size_t)row * ldo + c0;
#pragma unroll
    for (int q = 0; q < 4; q++){
        float4 v;
        v.x = acc[q*4+0]; v.y = acc[q*4+1]; v.z = acc[q*4+2]; v.w = acc[q*4+3];
        if (bias){
            v.x += bias[c0+q*4+0]; v.y += bias[c0+q*4+1];
            v.z += bias[c0+q*4+2]; v.w += bias[c0+q*4+3];
        }
        if (act == 1){
            v.x = fmaxf(v.x, 0.f); v.y = fmaxf(v.y, 0.f);
            v.z = fmaxf(v.z, 0.f); v.w = fmaxf(v.w, 0.f);
        }
        *(float4*)(o + q*4) = v;
    }
}

// ---------------- GIN aggregation: hpre[n,128] = xc[n] + sum_{e in} xc[src] ----
__global__ __launch_bounds__(256) void gin_agg(
        const float* __restrict__ xc, const int* __restrict__ off,
        const int* __restrict__ csr, float* __restrict__ hpre, int n)
{
    int node = __builtin_amdgcn_readfirstlane(blockIdx.x * 4 + (threadIdx.x >> 6));
    int lane = threadIdx.x & 63;
    if (node >= n) return;
    int beg = off[node], end = off[node+1];
    float a0 = xc[(size_t)node*128 + lane];
    float a1 = xc[(size_t)node*128 + 64 + lane];
    int e = beg;
    for (; e + 4 <= end; e += 4){
        int s0 = csr[e], s1 = csr[e+1], s2 = csr[e+2], s3 = csr[e+3];
        float v0 = xc[(size_t)s0*128 + lane],      w0 = xc[(size_t)s0*128 + 64 + lane];
        float v1 = xc[(size_t)s1*128 + lane],      w1 = xc[(size_t)s1*128 + 64 + lane];
        float v2 = xc[(size_t)s2*128 + lane],      w2 = xc[(size_t)s2*128 + 64 + lane];
        float v3 = xc[(size_t)s3*128 + lane],      w3 = xc[(size_t)s3*128 + 64 + lane];
        a0 += (v0 + v1) + (v2 + v3);
        a1 += (w0 + w1) + (w2 + w3);
    }
    for (; e < end; e++){
        int s0 = csr[e];
        a0 += xc[(size_t)s0*128 + lane];
        a1 += xc[(size_t)s0*128 + 64 + lane];
    }
    hpre[(size_t)node*128 + lane]      = a0;
    hpre[(size_t)node*128 + 64 + lane] = a1;
}

// ---------------- GCN aggregation + self + tanh; writes s into xc right half ----
__global__ __launch_bounds__(256) void gcn_agg(
        const float* __restrict__ hs, const float* __restrict__ dinv,
        const int* __restrict__ off, const int* __restrict__ csr,
        const float* __restrict__ bias, float* __restrict__ xc, int n)
{
    int node = __builtin_amdgcn_readfirstlane(blockIdx.x * 4 + (threadIdx.x >> 6));
    int lane = threadIdx.x & 63;
    if (node >= n) return;
    int beg = off[node], end = off[node+1];
    float acc = 0.f;
    int e = beg;
    for (; e + 4 <= end; e += 4){
        int s0 = csr[e], s1 = csr[e+1], s2 = csr[e+2], s3 = csr[e+3];
        float v0 = dinv[s0] * hs[(size_t)s0*64 + lane];
        float v1 = dinv[s1] * hs[(size_t)s1*64 + lane];
        float v2 = dinv[s2] * hs[(size_t)s2*64 + lane];
        float v3 = dinv[s3] * hs[(size_t)s3*64 + lane];
        acc += (v0 + v1) + (v2 + v3);
    }
    for (; e < end; e++){
        int s0 = csr[e];
        acc += dinv[s0] * hs[(size_t)s0*64 + lane];
    }
    float di   = dinv[node];
    float self = hs[(size_t)node*64 + lane];
    float v = tanhf(di*acc + self*di*di + bias[lane]);
    xc[(size_t)node*128 + 64 + lane] = v;
}

// ---------------- global_add_pool (batch sorted, int32) -------------------
__global__ __launch_bounds__(64) void pool_kernel(
        const float* __restrict__ xw, const int* __restrict__ batch,
        float* __restrict__ g, int n)
{
    int lane = threadIdx.x;
    int r0 = blockIdx.x * 128;
    if (r0 >= n) return;
    int r1 = r0 + 128; if (r1 > n) r1 = n;
    float acc = 0.f;
    int cb = batch[r0];
    for (int r = r0; r < r1; r++){
        int b = batch[r];
        if (b != cb){
            atomicAdd(&g[(size_t)cb*64 + lane], acc);
            acc = 0.f; cb = b;
        }
        acc += xw[(size_t)r*64 + lane];
    }
    atomicAdd(&g[(size_t)cb*64 + lane], acc);
}

// ---------------- head: relu(g@postW+b) @ roW + b -> log_softmax ----------
__global__ __launch_bounds__(256) void head_kernel(
        const float* __restrict__ g, const float* __restrict__ postW,
        const float* __restrict__ postb, const float* __restrict__ roW,
        const float* __restrict__ rob, float* __restrict__ out, int ngraph)
{
    int gr = __builtin_amdgcn_readfirstlane(blockIdx.x * 4 + (threadIdx.x >> 6));
    int lane = threadIdx.x & 63;
    if (gr >= ngraph) return;
    float gv = g[(size_t)gr*64 + lane];
    float t = postb[lane];
    for (int k = 0; k < 64; k++){
        float a = __shfl(gv, k);
        t = fmaf(a, postW[k*64 + lane], t);
    }
    t = fmaxf(t, 0.f);
    float lg = (lane < NCLS) ? rob[lane] : 0.f;
    for (int k = 0; k < 64; k++){
        float a = __shfl(t, k);
        float w = (lane < NCLS) ? roW[k*NCLS + lane] : 0.f;
        lg = fmaf(a, w, lg);
    }
    float m = (lane < NCLS) ? lg : -INFINITY;
#pragma unroll
    for (int d = 1; d < 16; d <<= 1) m = fmaxf(m, __shfl_xor(m, d, 16));
    float ex = (lane < NCLS) ? expf(lg - m) : 0.f;
    float ssum = ex;
#pragma unroll
    for (int d = 1; d < 16; d <<= 1) ssum += __shfl_xor(ssum, d, 16);
    if (lane < NCLS) out[(size_t)gr*NCLS + lane] = lg - m - logf(ssum);
}

// ---------------- launch --------------------------------------------------
extern "C" void kernel_launch(void* const* d_in, const int* in_sizes, int n_in,
                              void* d_out, int out_size, void* d_ws, size_t ws_size,
                              hipStream_t stream) {
    const float* x      = (const float*)d_in[0];
    const float* s      = (const float*)d_in[1];
    const int*   ei     = (const int*)d_in[2];    // int32! (harness downcasts int64)
    const int*   batch  = (const int*)d_in[3];    // int32!
    const float* pre_W  = (const float*)d_in[4];
    const float* pre_b  = (const float*)d_in[5];
    const float* emb_W  = (const float*)d_in[6];
    const float* emb_b  = (const float*)d_in[7];
    const float* gin_W1 = (const float*)d_in[8];
    const float* gin_b1 = (const float*)d_in[9];
    const float* gin_W2 = (const float*)d_in[10];
    const float* gin_b2 = (const float*)d_in[11];
    const float* gcn_W  = (const float*)d_in[12];
    const float* gcn_b  = (const float*)d_in[13];
    const float* whp_W  = (const float*)d_in[14];
    const float* whp_b  = (const float*)d_in[15];
    const float* post_W = (const float*)d_in[16];
    const float* post_b = (const float*)d_in[17];
    const float* ro_W   = (const float*)d_in[18];
    const float* ro_b   = (const float*)d_in[19];
    float* out = (float*)d_out;

    char* w = (char*)d_ws;
    auto alloc = [&](size_t bytes) -> void* {
        void* p = (void*)w;
        w += (bytes + 255) & ~(size_t)255;
        return p;
    };
    int*   cnt  = (int*)  alloc((size_t)NN * 4);
    int*   off  = (int*)  alloc((size_t)(NN+1) * 4);
    int*   cur  = (int*)  alloc((size_t)NN * 4);
    int*   csr  = (int*)  alloc((size_t)NE * 4);
    float* dinv = (float*)alloc((size_t)NN * 4);
    float* xc   = (float*)alloc((size_t)NN * 128 * 4);
    float* hpre = (float*)alloc((size_t)NN * 128 * 4);   // aliased as hs in GCN phase
    float* h1   = (float*)alloc((size_t)NN * 64 * 4);    // aliased as xw after layers
    float* gbuf = (float*)alloc((size_t)NG * 64 * 4);
    float* hs = hpre;
    float* xw = h1;

    const int B = 256;
    // CSR build
    zero_i32<<<(NN + B-1)/B, B, 0, stream>>>(cnt, NN);
    count_deg<<<(NE + B-1)/B, B, 0, stream>>>(ei + NE, cnt, NE);
    scan_off<<<1, 1024, 0, stream>>>(cnt, off, cur, dinv, NN, NE);
    fill_csr<<<(NE + B-1)/B, B, 0, stream>>>(ei, ei + NE, cur, csr, NE);

    const int GL = (NN + 63) / 64;   // linear64 grid
    const int GA = (NN + 3) / 4;     // agg grid

    // pre / emb -> xc = [x | s]
    linear64<FEATD><<<GL, B, 0, stream>>>(x, FEATD, pre_W, pre_b, xc,      128, NN, 0);
    linear64<SED>  <<<GL, B, 0, stream>>>(s, SED,   emb_W, emb_b, xc + 64, 128, NN, 0);

    for (int i = 0; i < NLAY; i++){
        gin_agg<<<GA, B, 0, stream>>>(xc, off, csr, hpre, NN);
        linear64<128><<<GL, B, 0, stream>>>(hpre, 128, gin_W1 + (size_t)i*128*64,
                                            gin_b1 + i*64, h1, 64, NN, 1);
        linear64<64> <<<GL, B, 0, stream>>>(h1, 64, gin_W2 + (size_t)i*64*64,
                                            gin_b2 + i*64, xc, 128, NN, 1);
        linear64<64> <<<GL, B, 0, stream>>>(xc + 64, 128, gcn_W + (size_t)i*64*64,
                                            nullptr, hs, 64, NN, 0);
        gcn_agg<<<GA, B, 0, stream>>>(hs, dinv, off, csr, gcn_b + i*64, xc, NN);
    }

    // whp -> xw
    linear64<128><<<GL, B, 0, stream>>>(xc, 128, whp_W, whp_b, xw, 64, NN, 0);

    // pool
    zero_f32<<<(NG*64 + B-1)/B, B, 0, stream>>>(gbuf, NG*64);
    pool_kernel<<<(NN + 127)/128, 64, 0, stream>>>(xw, batch, gbuf, NN);

    // head
    head_kernel<<<(NG + 3)/4, B, 0, stream>>>(gbuf, post_W, post_b, ro_W, ro_b, out, NG);
}

// Round 3
// 718.647 us; speedup vs baseline: 1.1706x; 1.1706x over previous
//
#include <hip/hip_runtime.h>
#include <math.h>

#define NN   50000
#define NE   800000
#define FEATD 128
#define SED  16
#define HD   64
#define NCLS 10
#define NLAY 3
#define NG   500

#define SBLK 256
#define SNB  ((NN + SBLK - 1) / SBLK)   // 196 blocks

// ---------------- utility zero kernels (d_ws is poisoned 0xAA each call) ---
__global__ void zero_i32(int* __restrict__ p, int n){
    int i = blockIdx.x*blockDim.x + threadIdx.x;
    if (i < n) p[i] = 0;
}
__global__ void zero_f32(float* __restrict__ p, int n){
    int i = blockIdx.x*blockDim.x + threadIdx.x;
    if (i < n) p[i] = 0.f;
}

// ---------------- CSR build ------------------------------------------------
// NOTE: harness delivers integer inputs as int32 (const int*), NOT int64.
__global__ void count_deg(const int* __restrict__ dst, int* __restrict__ cnt, int e){
    int i = blockIdx.x*blockDim.x + threadIdx.x;
    if (i < e) atomicAdd(&cnt[dst[i]], 1);
}

// ---- hierarchical exclusive scan of cnt[NN] -> off/cur, plus dinv ---------
// k1: per-block inclusive scan in LDS; off[i] = local exclusive; bsum[b] = total
__global__ __launch_bounds__(SBLK) void scan_local(
        const int* __restrict__ cnt, int* __restrict__ off, int* __restrict__ bsum, int n){
    __shared__ int sh[SBLK];
    int t = threadIdx.x;
    int i = blockIdx.x * SBLK + t;
    int v = (i < n) ? cnt[i] : 0;
    sh[t] = v;
    __syncthreads();
#pragma unroll
    for (int d = 1; d < SBLK; d <<= 1){
        int u = (t >= d) ? sh[t-d] : 0;
        __syncthreads();
        sh[t] += u;
        __syncthreads();
    }
    if (i < n) off[i] = sh[t] - v;          // exclusive within block
    if (t == SBLK-1) bsum[blockIdx.x] = sh[t];
}

// k2: single block scans bsum[SNB] -> exclusive block offsets (in place)
__global__ __launch_bounds__(SBLK) void scan_bsum(int* __restrict__ bsum, int nb){
    __shared__ int sh[SBLK];
    int t = threadIdx.x;
    int v = (t < nb) ? bsum[t] : 0;
    sh[t] = v;
    __syncthreads();
#pragma unroll
    for (int d = 1; d < SBLK; d <<= 1){
        int u = (t >= d) ? sh[t-d] : 0;
        __syncthreads();
        sh[t] += u;
        __syncthreads();
    }
    if (t < nb) bsum[t] = sh[t] - v;        // exclusive
}

// k3: finalize off/cur/dinv
__global__ __launch_bounds__(SBLK) void scan_finish(
        int* __restrict__ off, int* __restrict__ cur, const int* __restrict__ cnt,
        const int* __restrict__ bsum, float* __restrict__ dinv, int n, int etot){
    int i = blockIdx.x * SBLK + threadIdx.x;
    if (i < n){
        int o = off[i] + bsum[blockIdx.x];
        off[i] = o; cur[i] = o;
        dinv[i] = rsqrtf((float)cnt[i] + 1.0f);
    }
    if (i == 0) off[n] = etot;
}

__global__ void fill_csr(const int* __restrict__ src, const int* __restrict__ dst,
        int* __restrict__ cur, int* __restrict__ csr, int e){
    int i = blockIdx.x*blockDim.x + threadIdx.x;
    if (i < e){
        int d = dst[i];
        int p = atomicAdd(&cur[d], 1);
        csr[p] = src[i];
    }
}

// ---------------- fp32 tall-skinny linear: out[n,64] = A[n,K]@W[K,64] (+b, act) ---
// Each wave handles 64 rows (lane=row) and a wave-uniform group of 16 cols so W
// goes through scalar loads. act: 0=none, 1=relu.
template<int K>
__global__ __launch_bounds__(256) void linear64(
        const float* __restrict__ A, int lda,
        const float* __restrict__ W,
        const float* __restrict__ bias,
        float* __restrict__ out, int ldo, int n, int act)
{
    int lane = threadIdx.x & 63;
    int c0 = __builtin_amdgcn_readfirstlane((threadIdx.x >> 6) << 4);
    int row = blockIdx.x * 64 + lane;
    if (row >= n) return;
    float acc[16];
#pragma unroll
    for (int j = 0; j < 16; j++) acc[j] = 0.f;
    const float* a  = A + (size_t)row * lda;
    const float* wp = W + c0;
    for (int k = 0; k < K; k += 4){
        float4 av = *(const float4*)(a + k);
        float aa[4] = {av.x, av.y, av.z, av.w};
#pragma unroll
        for (int kk = 0; kk < 4; kk++){
            const float* wr = wp + (k + kk) * 64;
#pragma unroll
            for (int j = 0; j < 16; j++)
                acc[j] = fmaf(aa[kk], wr[j], acc[j]);
        }
    }
    float* o = out + (size_t)row * ldo + c0;
#pragma unroll
    for (int q = 0; q < 4; q++){
        float4 v;
        v.x = acc[q*4+0]; v.y = acc[q*4+1]; v.z = acc[q*4+2]; v.w = acc[q*4+3];
        if (bias){
            v.x += bias[c0+q*4+0]; v.y += bias[c0+q*4+1];
            v.z += bias[c0+q*4+2]; v.w += bias[c0+q*4+3];
        }
        if (act == 1){
            v.x = fmaxf(v.x, 0.f); v.y = fmaxf(v.y, 0.f);
            v.z = fmaxf(v.z, 0.f); v.w = fmaxf(v.w, 0.f);
        }
        *(float4*)(o + q*4) = v;
    }
}

// ---------------- GIN aggregation: hpre[n,128] = xc[n] + sum_{e in} xc[src] ----
__global__ __launch_bounds__(256) void gin_agg(
        const float* __restrict__ xc, const int* __restrict__ off,
        const int* __restrict__ csr, float* __restrict__ hpre, int n)
{
    int node = __builtin_amdgcn_readfirstlane(blockIdx.x * 4 + (threadIdx.x >> 6));
    int lane = threadIdx.x & 63;
    if (node >= n) return;
    int beg = off[node], end = off[node+1];
    float a0 = xc[(size_t)node*128 + lane];
    float a1 = xc[(size_t)node*128 + 64 + lane];
    int e = beg;
    for (; e + 4 <= end; e += 4){
        int s0 = csr[e], s1 = csr[e+1], s2 = csr[e+2], s3 = csr[e+3];
        float v0 = xc[(size_t)s0*128 + lane],      w0 = xc[(size_t)s0*128 + 64 + lane];
        float v1 = xc[(size_t)s1*128 + lane],      w1 = xc[(size_t)s1*128 + 64 + lane];
        float v2 = xc[(size_t)s2*128 + lane],      w2 = xc[(size_t)s2*128 + 64 + lane];
        float v3 = xc[(size_t)s3*128 + lane],      w3 = xc[(size_t)s3*128 + 64 + lane];
        a0 += (v0 + v1) + (v2 + v3);
        a1 += (w0 + w1) + (w2 + w3);
    }
    for (; e < end; e++){
        int s0 = csr[e];
        a0 += xc[(size_t)s0*128 + lane];
        a1 += xc[(size_t)s0*128 + 64 + lane];
    }
    hpre[(size_t)node*128 + lane]      = a0;
    hpre[(size_t)node*128 + 64 + lane] = a1;
}

// ---------------- GCN aggregation + self + tanh; writes s into xc right half ----
__global__ __launch_bounds__(256) void gcn_agg(
        const float* __restrict__ hs, const float* __restrict__ dinv,
        const int* __restrict__ off, const int* __restrict__ csr,
        const float* __restrict__ bias, float* __restrict__ xc, int n)
{
    int node = __builtin_amdgcn_readfirstlane(blockIdx.x * 4 + (threadIdx.x >> 6));
    int lane = threadIdx.x & 63;
    if (node >= n) return;
    int beg = off[node], end = off[node+1];
    float acc = 0.f;
    int e = beg;
    for (; e + 4 <= end; e += 4){
        int s0 = csr[e], s1 = csr[e+1], s2 = csr[e+2], s3 = csr[e+3];
        float v0 = dinv[s0] * hs[(size_t)s0*64 + lane];
        float v1 = dinv[s1] * hs[(size_t)s1*64 + lane];
        float v2 = dinv[s2] * hs[(size_t)s2*64 + lane];
        float v3 = dinv[s3] * hs[(size_t)s3*64 + lane];
        acc += (v0 + v1) + (v2 + v3);
    }
    for (; e < end; e++){
        int s0 = csr[e];
        acc += dinv[s0] * hs[(size_t)s0*64 + lane];
    }
    float di   = dinv[node];
    float self = hs[(size_t)node*64 + lane];
    float v = tanhf(di*acc + self*di*di + bias[lane]);
    xc[(size_t)node*128 + 64 + lane] = v;
}

// ---------------- global_add_pool (batch sorted, int32) -------------------
__global__ __launch_bounds__(64) void pool_kernel(
        const float* __restrict__ xw, const int* __restrict__ batch,
        float* __restrict__ g, int n)
{
    int lane = threadIdx.x;
    int r0 = blockIdx.x * 128;
    if (r0 >= n) return;
    int r1 = r0 + 128; if (r1 > n) r1 = n;
    float acc = 0.f;
    int cb = batch[r0];
    for (int r = r0; r < r1; r++){
        int b = batch[r];
        if (b != cb){
            atomicAdd(&g[(size_t)cb*64 + lane], acc);
            acc = 0.f; cb = b;
        }
        acc += xw[(size_t)r*64 + lane];
    }
    atomicAdd(&g[(size_t)cb*64 + lane], acc);
}

// ---------------- head: relu(g@postW+b) @ roW + b -> log_softmax ----------
__global__ __launch_bounds__(256) void head_kernel(
        const float* __restrict__ g, const float* __restrict__ postW,
        const float* __restrict__ postb, const float* __restrict__ roW,
        const float* __restrict__ rob, float* __restrict__ out, int ngraph)
{
    int gr = __builtin_amdgcn_readfirstlane(blockIdx.x * 4 + (threadIdx.x >> 6));
    int lane = threadIdx.x & 63;
    if (gr >= ngraph) return;
    float gv = g[(size_t)gr*64 + lane];
    float t = postb[lane];
    for (int k = 0; k < 64; k++){
        float a = __shfl(gv, k);
        t = fmaf(a, postW[k*64 + lane], t);
    }
    t = fmaxf(t, 0.f);
    float lg = (lane < NCLS) ? rob[lane] : 0.f;
    for (int k = 0; k < 64; k++){
        float a = __shfl(t, k);
        float w = (lane < NCLS) ? roW[k*NCLS + lane] : 0.f;
        lg = fmaf(a, w, lg);
    }
    float m = (lane < NCLS) ? lg : -INFINITY;
#pragma unroll
    for (int d = 1; d < 16; d <<= 1) m = fmaxf(m, __shfl_xor(m, d, 16));
    float ex = (lane < NCLS) ? expf(lg - m) : 0.f;
    float ssum = ex;
#pragma unroll
    for (int d = 1; d < 16; d <<= 1) ssum += __shfl_xor(ssum, d, 16);
    if (lane < NCLS) out[(size_t)gr*NCLS + lane] = lg - m - logf(ssum);
}

// ---------------- launch --------------------------------------------------
extern "C" void kernel_launch(void* const* d_in, const int* in_sizes, int n_in,
                              void* d_out, int out_size, void* d_ws, size_t ws_size,
                              hipStream_t stream) {
    const float* x      = (const float*)d_in[0];
    const float* s      = (const float*)d_in[1];
    const int*   ei     = (const int*)d_in[2];    // int32 (harness downcasts int64)
    const int*   batch  = (const int*)d_in[3];    // int32
    const float* pre_W  = (const float*)d_in[4];
    const float* pre_b  = (const float*)d_in[5];
    const float* emb_W  = (const float*)d_in[6];
    const float* emb_b  = (const float*)d_in[7];
    const float* gin_W1 = (const float*)d_in[8];
    const float* gin_b1 = (const float*)d_in[9];
    const float* gin_W2 = (const float*)d_in[10];
    const float* gin_b2 = (const float*)d_in[11];
    const float* gcn_W  = (const float*)d_in[12];
    const float* gcn_b  = (const float*)d_in[13];
    const float* whp_W  = (const float*)d_in[14];
    const float* whp_b  = (const float*)d_in[15];
    const float* post_W = (const float*)d_in[16];
    const float* post_b = (const float*)d_in[17];
    const float* ro_W   = (const float*)d_in[18];
    const float* ro_b   = (const float*)d_in[19];
    float* out = (float*)d_out;

    char* w = (char*)d_ws;
    auto alloc = [&](size_t bytes) -> void* {
        void* p = (void*)w;
        w += (bytes + 255) & ~(size_t)255;
        return p;
    };
    int*   cnt  = (int*)  alloc((size_t)NN * 4);
    int*   off  = (int*)  alloc((size_t)(NN+1) * 4);
    int*   cur  = (int*)  alloc((size_t)NN * 4);
    int*   csr  = (int*)  alloc((size_t)NE * 4);
    int*   bsum = (int*)  alloc((size_t)SNB * 4);
    float* dinv = (float*)alloc((size_t)NN * 4);
    float* xc   = (float*)alloc((size_t)NN * 128 * 4);
    float* hpre = (float*)alloc((size_t)NN * 128 * 4);   // aliased as hs in GCN phase
    float* h1   = (float*)alloc((size_t)NN * 64 * 4);    // aliased as xw after layers
    float* gbuf = (float*)alloc((size_t)NG * 64 * 4);
    float* hs = hpre;
    float* xw = h1;

    const int B = 256;
    // CSR build (hierarchical scan: 3 tiny dispatches instead of 1-block serial)
    zero_i32<<<(NN + B-1)/B, B, 0, stream>>>(cnt, NN);
    count_deg<<<(NE + B-1)/B, B, 0, stream>>>(ei + NE, cnt, NE);
    scan_local <<<SNB, SBLK, 0, stream>>>(cnt, off, bsum, NN);
    scan_bsum  <<<1,   SBLK, 0, stream>>>(bsum, SNB);
    scan_finish<<<SNB, SBLK, 0, stream>>>(off, cur, cnt, bsum, dinv, NN, NE);
    fill_csr<<<(NE + B-1)/B, B, 0, stream>>>(ei, ei + NE, cur, csr, NE);

    const int GL = (NN + 63) / 64;   // linear64 grid
    const int GA = (NN + 3) / 4;     // agg grid

    // pre / emb -> xc = [x | s]
    linear64<FEATD><<<GL, B, 0, stream>>>(x, FEATD, pre_W, pre_b, xc,      128, NN, 0);
    linear64<SED>  <<<GL, B, 0, stream>>>(s, SED,   emb_W, emb_b, xc + 64, 128, NN, 0);

    for (int i = 0; i < NLAY; i++){
        gin_agg<<<GA, B, 0, stream>>>(xc, off, csr, hpre, NN);
        linear64<128><<<GL, B, 0, stream>>>(hpre, 128, gin_W1 + (size_t)i*128*64,
                                            gin_b1 + i*64, h1, 64, NN, 1);
        linear64<64> <<<GL, B, 0, stream>>>(h1, 64, gin_W2 + (size_t)i*64*64,
                                            gin_b2 + i*64, xc, 128, NN, 1);
        linear64<64> <<<GL, B, 0, stream>>>(xc + 64, 128, gcn_W + (size_t)i*64*64,
                                            nullptr, hs, 64, NN, 0);
        gcn_agg<<<GA, B, 0, stream>>>(hs, dinv, off, csr, gcn_b + i*64, xc, NN);
    }

    // whp -> xw
    linear64<128><<<GL, B, 0, stream>>>(xc, 128, whp_W, whp_b, xw, 64, NN, 0);

    // pool
    zero_f32<<<(NG*64 + B-1)/B, B, 0, stream>>>(gbuf, NG*64);
    pool_kernel<<<(NN + 127)/128, 64, 0, stream>>>(xw, batch, gbuf, NN);

    // head
    head_kernel<<<(NG + 3)/4, B, 0, stream>>>(gbuf, post_W, post_b, ro_W, ro_b, out, NG);
}

// Round 4
// 651.505 us; speedup vs baseline: 1.2913x; 1.1031x over previous
//
#include <hip/hip_runtime.h>
#include <math.h>

#define NN   50000
#define NE   800000
#define FEATD 128
#define SED  16
#define HD   64
#define NCLS 10
#define NLAY 3
#define NG   500

#define SBLK 256
#define SNB  ((NN + SBLK - 1) / SBLK)   // 196 blocks

// ---- bf16 helpers (round-to-nearest-even pack; unpack via shift) ----------
__device__ inline unsigned short f2bf(float f){
    unsigned int u = __float_as_uint(f);
    u += 0x7fffu + ((u >> 16) & 1u);
    return (unsigned short)(u >> 16);
}
__device__ inline float bf_lo(unsigned int p){ return __uint_as_float(p << 16); }
__device__ inline float bf_hi(unsigned int p){ return __uint_as_float(p & 0xffff0000u); }

// ---------------- utility zero kernels ------------------------------------
__global__ void zero_i32(int* __restrict__ p, int n){
    int i = blockIdx.x*blockDim.x + threadIdx.x;
    if (i < n) p[i] = 0;
}
__global__ void zero_f32(float* __restrict__ p, int n){
    int i = blockIdx.x*blockDim.x + threadIdx.x;
    if (i < n) p[i] = 0.f;
}

// ---------------- CSR build ------------------------------------------------
// harness delivers integer inputs as int32 (const int*), NOT int64.
__global__ void count_deg(const int* __restrict__ dst, int* __restrict__ cnt, int e){
    int i = blockIdx.x*blockDim.x + threadIdx.x;
    if (i < e) atomicAdd(&cnt[dst[i]], 1);
}

__global__ __launch_bounds__(SBLK) void scan_local(
        const int* __restrict__ cnt, int* __restrict__ off, int* __restrict__ bsum, int n){
    __shared__ int sh[SBLK];
    int t = threadIdx.x;
    int i = blockIdx.x * SBLK + t;
    int v = (i < n) ? cnt[i] : 0;
    sh[t] = v;
    __syncthreads();
#pragma unroll
    for (int d = 1; d < SBLK; d <<= 1){
        int u = (t >= d) ? sh[t-d] : 0;
        __syncthreads();
        sh[t] += u;
        __syncthreads();
    }
    if (i < n) off[i] = sh[t] - v;
    if (t == SBLK-1) bsum[blockIdx.x] = sh[t];
}

__global__ __launch_bounds__(SBLK) void scan_bsum(int* __restrict__ bsum, int nb){
    __shared__ int sh[SBLK];
    int t = threadIdx.x;
    int v = (t < nb) ? bsum[t] : 0;
    sh[t] = v;
    __syncthreads();
#pragma unroll
    for (int d = 1; d < SBLK; d <<= 1){
        int u = (t >= d) ? sh[t-d] : 0;
        __syncthreads();
        sh[t] += u;
        __syncthreads();
    }
    if (t < nb) bsum[t] = sh[t] - v;
}

__global__ __launch_bounds__(SBLK) void scan_finish(
        int* __restrict__ off, int* __restrict__ cur, const int* __restrict__ cnt,
        const int* __restrict__ bsum, float* __restrict__ dinv, int n, int etot){
    int i = blockIdx.x * SBLK + threadIdx.x;
    if (i < n){
        int o = off[i] + bsum[blockIdx.x];
        off[i] = o; cur[i] = o;
        dinv[i] = rsqrtf((float)cnt[i] + 1.0f);
    }
    if (i == 0) off[n] = etot;
}

__global__ void fill_csr(const int* __restrict__ src, const int* __restrict__ dst,
        int* __restrict__ cur, int* __restrict__ csr, int e){
    int i = blockIdx.x*blockDim.x + threadIdx.x;
    if (i < e){
        int d = dst[i];
        int p = atomicAdd(&cur[d], 1);
        csr[p] = src[i];
    }
}

// ---------------- fp32 tall-skinny linear: out[n,64] = A[n,K]@W[K,64] -----
// wave: lane=row, wave-uniform 16-col group. Optional bf16 shadow output.
template<int K>
__global__ __launch_bounds__(256) void linear64(
        const float* __restrict__ A, int lda,
        const float* __restrict__ W,
        const float* __restrict__ bias,
        float* __restrict__ out, int ldo,
        unsigned short* __restrict__ outb, int ldob,
        int n, int act)
{
    int lane = threadIdx.x & 63;
    int c0 = __builtin_amdgcn_readfirstlane((threadIdx.x >> 6) << 4);
    int row = blockIdx.x * 64 + lane;
    if (row >= n) return;
    float acc[16];
#pragma unroll
    for (int j = 0; j < 16; j++) acc[j] = 0.f;
    const float* a  = A + (size_t)row * lda;
    const float* wp = W + c0;
    for (int k = 0; k < K; k += 4){
        float4 av = *(const float4*)(a + k);
        float aa[4] = {av.x, av.y, av.z, av.w};
#pragma unroll
        for (int kk = 0; kk < 4; kk++){
            const float* wr = wp + (k + kk) * 64;
#pragma unroll
            for (int j = 0; j < 16; j++)
                acc[j] = fmaf(aa[kk], wr[j], acc[j]);
        }
    }
    if (bias){
#pragma unroll
        for (int j = 0; j < 16; j++) acc[j] += bias[c0 + j];
    }
    if (act == 1){
#pragma unroll
        for (int j = 0; j < 16; j++) acc[j] = fmaxf(acc[j], 0.f);
    }
    float* o = out + (size_t)row * ldo + c0;
#pragma unroll
    for (int q = 0; q < 4; q++){
        float4 v;
        v.x = acc[q*4+0]; v.y = acc[q*4+1]; v.z = acc[q*4+2]; v.w = acc[q*4+3];
        *(float4*)(o + q*4) = v;
    }
    if (outb){
        unsigned int pk[8];
#pragma unroll
        for (int j = 0; j < 8; j++)
            pk[j] = (unsigned int)f2bf(acc[2*j]) | ((unsigned int)f2bf(acc[2*j+1]) << 16);
        unsigned short* ob = outb + (size_t)row * ldob + c0;
        uint4 u0; u0.x = pk[0]; u0.y = pk[1]; u0.z = pk[2]; u0.w = pk[3];
        uint4 u1; u1.x = pk[4]; u1.y = pk[5]; u1.z = pk[6]; u1.w = pk[7];
        *(uint4*)(ob)     = u0;
        *(uint4*)(ob + 8) = u1;
    }
}

// ---------------- GIN aggregation (bf16 gather table) ----------------------
// hpre[n,128] = xc[n] + sum_{e in} xcb[src]; lane handles cols (2L, 2L+1).
__global__ __launch_bounds__(256) void gin_agg(
        const float* __restrict__ xc, const unsigned int* __restrict__ xcb,
        const int* __restrict__ off, const int* __restrict__ csr,
        float* __restrict__ hpre, int n)
{
    int node = __builtin_amdgcn_readfirstlane(blockIdx.x * 4 + (threadIdx.x >> 6));
    int lane = threadIdx.x & 63;
    if (node >= n) return;
    int beg = off[node], end = off[node+1];
    float2 self = *(const float2*)(xc + (size_t)node*128 + 2*lane);
    float a0 = self.x, a1 = self.y;
    int e = beg;
    for (; e + 4 <= end; e += 4){
        int s0 = csr[e], s1 = csr[e+1], s2 = csr[e+2], s3 = csr[e+3];
        unsigned int p0 = xcb[(size_t)s0*64 + lane];
        unsigned int p1 = xcb[(size_t)s1*64 + lane];
        unsigned int p2 = xcb[(size_t)s2*64 + lane];
        unsigned int p3 = xcb[(size_t)s3*64 + lane];
        a0 += (bf_lo(p0) + bf_lo(p1)) + (bf_lo(p2) + bf_lo(p3));
        a1 += (bf_hi(p0) + bf_hi(p1)) + (bf_hi(p2) + bf_hi(p3));
    }
    for (; e < end; e++){
        unsigned int p0 = xcb[(size_t)csr[e]*64 + lane];
        a0 += bf_lo(p0);
        a1 += bf_hi(p0);
    }
    float2 r; r.x = a0; r.y = a1;
    *(float2*)(hpre + (size_t)node*128 + 2*lane) = r;
}

// ---------------- GCN aggregation (bf16 gather) + self + tanh --------------
// writes s into xc right half (fp32) AND xcb right half (bf16)
__global__ __launch_bounds__(256) void gcn_agg(
        const float* __restrict__ hs, const unsigned short* __restrict__ hsb,
        const float* __restrict__ dinv,
        const int* __restrict__ off, const int* __restrict__ csr,
        const float* __restrict__ bias, float* __restrict__ xc,
        unsigned short* __restrict__ xcb, int n)
{
    int node = __builtin_amdgcn_readfirstlane(blockIdx.x * 4 + (threadIdx.x >> 6));
    int lane = threadIdx.x & 63;
    if (node >= n) return;
    int beg = off[node], end = off[node+1];
    float acc = 0.f;
    int e = beg;
    for (; e + 4 <= end; e += 4){
        int s0 = csr[e], s1 = csr[e+1], s2 = csr[e+2], s3 = csr[e+3];
        float v0 = dinv[s0] * __uint_as_float((unsigned int)hsb[(size_t)s0*64 + lane] << 16);
        float v1 = dinv[s1] * __uint_as_float((unsigned int)hsb[(size_t)s1*64 + lane] << 16);
        float v2 = dinv[s2] * __uint_as_float((unsigned int)hsb[(size_t)s2*64 + lane] << 16);
        float v3 = dinv[s3] * __uint_as_float((unsigned int)hsb[(size_t)s3*64 + lane] << 16);
        acc += (v0 + v1) + (v2 + v3);
    }
    for (; e < end; e++){
        int s0 = csr[e];
        acc += dinv[s0] * __uint_as_float((unsigned int)hsb[(size_t)s0*64 + lane] << 16);
    }
    float di   = dinv[node];
    float self = hs[(size_t)node*64 + lane];
    float v = tanhf(di*acc + self*di*di + bias[lane]);
    xc [(size_t)node*128 + 64 + lane] = v;
    xcb[(size_t)node*128 + 64 + lane] = f2bf(v);
}

// ---------------- global_add_pool (batch sorted, int32) -------------------
__global__ __launch_bounds__(64) void pool_kernel(
        const float* __restrict__ xw, const int* __restrict__ batch,
        float* __restrict__ g, int n)
{
    int lane = threadIdx.x;
    int r0 = blockIdx.x * 128;
    if (r0 >= n) return;
    int r1 = r0 + 128; if (r1 > n) r1 = n;
    float acc = 0.f;
    int cb = batch[r0];
    for (int r = r0; r < r1; r++){
        int b = batch[r];
        if (b != cb){
            atomicAdd(&g[(size_t)cb*64 + lane], acc);
            acc = 0.f; cb = b;
        }
        acc += xw[(size_t)r*64 + lane];
    }
    atomicAdd(&g[(size_t)cb*64 + lane], acc);
}

// ---------------- head ----------------------------------------------------
__global__ __launch_bounds__(256) void head_kernel(
        const float* __restrict__ g, const float* __restrict__ postW,
        const float* __restrict__ postb, const float* __restrict__ roW,
        const float* __restrict__ rob, float* __restrict__ out, int ngraph)
{
    int gr = __builtin_amdgcn_readfirstlane(blockIdx.x * 4 + (threadIdx.x >> 6));
    int lane = threadIdx.x & 63;
    if (gr >= ngraph) return;
    float gv = g[(size_t)gr*64 + lane];
    float t = postb[lane];
    for (int k = 0; k < 64; k++){
        float a = __shfl(gv, k);
        t = fmaf(a, postW[k*64 + lane], t);
    }
    t = fmaxf(t, 0.f);
    float lg = (lane < NCLS) ? rob[lane] : 0.f;
    for (int k = 0; k < 64; k++){
        float a = __shfl(t, k);
        float w = (lane < NCLS) ? roW[k*NCLS + lane] : 0.f;
        lg = fmaf(a, w, lg);
    }
    float m = (lane < NCLS) ? lg : -INFINITY;
#pragma unroll
    for (int d = 1; d < 16; d <<= 1) m = fmaxf(m, __shfl_xor(m, d, 16));
    float ex = (lane < NCLS) ? expf(lg - m) : 0.f;
    float ssum = ex;
#pragma unroll
    for (int d = 1; d < 16; d <<= 1) ssum += __shfl_xor(ssum, d, 16);
    if (lane < NCLS) out[(size_t)gr*NCLS + lane] = lg - m - logf(ssum);
}

// ---------------- launch --------------------------------------------------
extern "C" void kernel_launch(void* const* d_in, const int* in_sizes, int n_in,
                              void* d_out, int out_size, void* d_ws, size_t ws_size,
                              hipStream_t stream) {
    const float* x      = (const float*)d_in[0];
    const float* s      = (const float*)d_in[1];
    const int*   ei     = (const int*)d_in[2];    // int32
    const int*   batch  = (const int*)d_in[3];    // int32
    const float* pre_W  = (const float*)d_in[4];
    const float* pre_b  = (const float*)d_in[5];
    const float* emb_W  = (const float*)d_in[6];
    const float* emb_b  = (const float*)d_in[7];
    const float* gin_W1 = (const float*)d_in[8];
    const float* gin_b1 = (const float*)d_in[9];
    const float* gin_W2 = (const float*)d_in[10];
    const float* gin_b2 = (const float*)d_in[11];
    const float* gcn_W  = (const float*)d_in[12];
    const float* gcn_b  = (const float*)d_in[13];
    const float* whp_W  = (const float*)d_in[14];
    const float* whp_b  = (const float*)d_in[15];
    const float* post_W = (const float*)d_in[16];
    const float* post_b = (const float*)d_in[17];
    const float* ro_W   = (const float*)d_in[18];
    const float* ro_b   = (const float*)d_in[19];
    float* out = (float*)d_out;

    char* w = (char*)d_ws;
    auto alloc = [&](size_t bytes) -> void* {
        void* p = (void*)w;
        w += (bytes + 255) & ~(size_t)255;
        return p;
    };
    int*   cnt  = (int*)  alloc((size_t)NN * 4);
    int*   off  = (int*)  alloc((size_t)(NN+1) * 4);
    int*   cur  = (int*)  alloc((size_t)NN * 4);
    int*   csr  = (int*)  alloc((size_t)NE * 4);
    int*   bsum = (int*)  alloc((size_t)SNB * 4);
    float* dinv = (float*)alloc((size_t)NN * 4);
    float* xc   = (float*)alloc((size_t)NN * 128 * 4);
    unsigned short* xcb = (unsigned short*)alloc((size_t)NN * 128 * 2);  // bf16 shadow of xc
    float* hpre = (float*)alloc((size_t)NN * 128 * 4);   // aliased as hs in GCN phase
    unsigned short* hsb = (unsigned short*)alloc((size_t)NN * 64 * 2);   // bf16 shadow of hs
    float* h1   = (float*)alloc((size_t)NN * 64 * 4);    // aliased as xw after layers
    float* gbuf = (float*)alloc((size_t)NG * 64 * 4);
    float* hs = hpre;
    float* xw = h1;

    const int B = 256;
    // CSR build
    zero_i32<<<(NN + B-1)/B, B, 0, stream>>>(cnt, NN);
    count_deg<<<(NE + B-1)/B, B, 0, stream>>>(ei + NE, cnt, NE);
    scan_local <<<SNB, SBLK, 0, stream>>>(cnt, off, bsum, NN);
    scan_bsum  <<<1,   SBLK, 0, stream>>>(bsum, SNB);
    scan_finish<<<SNB, SBLK, 0, stream>>>(off, cur, cnt, bsum, dinv, NN, NE);
    fill_csr<<<(NE + B-1)/B, B, 0, stream>>>(ei, ei + NE, cur, csr, NE);

    const int GL = (NN + 63) / 64;   // linear64 grid
    const int GA = (NN + 3) / 4;     // agg grid

    // pre / emb -> xc = [x | s], with bf16 shadow
    linear64<FEATD><<<GL, B, 0, stream>>>(x, FEATD, pre_W, pre_b, xc,      128, xcb,      128, NN, 0);
    linear64<SED>  <<<GL, B, 0, stream>>>(s, SED,   emb_W, emb_b, xc + 64, 128, xcb + 64, 128, NN, 0);

    for (int i = 0; i < NLAY; i++){
        gin_agg<<<GA, B, 0, stream>>>(xc, (const unsigned int*)xcb, off, csr, hpre, NN);
        linear64<128><<<GL, B, 0, stream>>>(hpre, 128, gin_W1 + (size_t)i*128*64,
                                            gin_b1 + i*64, h1, 64, nullptr, 0, NN, 1);
        linear64<64> <<<GL, B, 0, stream>>>(h1, 64, gin_W2 + (size_t)i*64*64,
                                            gin_b2 + i*64, xc, 128, xcb, 128, NN, 1);
        linear64<64> <<<GL, B, 0, stream>>>(xc + 64, 128, gcn_W + (size_t)i*64*64,
                                            nullptr, hs, 64, hsb, 64, NN, 0);
        gcn_agg<<<GA, B, 0, stream>>>(hs, hsb, dinv, off, csr, gcn_b + i*64, xc, xcb, NN);
    }

    // whp -> xw
    linear64<128><<<GL, B, 0, stream>>>(xc, 128, whp_W, whp_b, xw, 64, nullptr, 0, NN, 0);

    // pool
    zero_f32<<<(NG*64 + B-1)/B, B, 0, stream>>>(gbuf, NG*64);
    pool_kernel<<<(NN + 127)/128, 64, 0, stream>>>(xw, batch, gbuf, NN);

    // head
    head_kernel<<<(NG + 3)/4, B, 0, stream>>>(gbuf, post_W, post_b, ro_W, ro_b, out, NG);
}